// Round 8
// baseline (613.976 us; speedup 1.0000x reference)
//
#include <hip/hip_runtime.h>
#include <hip/hip_bf16.h>

typedef __hip_bfloat16 bf16;

#define NPTS  32768
#define NPB   4096
#define NPAIR (NPTS*16)
#define IMASK 32767
#define EPSB  1e-5f

// packed fp32 param-block offsets (floats)
#define O_WQ  0
#define O_BQ  4096
#define O_WK  4160
#define O_BK  8256
#define O_WV  8320
#define O_BV  12416
#define O_WP1 12480
#define O_BP1 12489
#define O_GP  12492
#define O_BTP 12495
#define O_WP2 12498
#define O_BP2 12690
#define O_G1  12754
#define O_BT1 12818
#define O_WW1 12882
#define O_BW1 13394
#define O_G2  13402
#define O_BT2 13410
#define O_WW2 13418
#define O_BW2 13482
#define NPRM  13490

__device__ __forceinline__ float b2f(bf16 v){ return __bfloat162float(v); }
__device__ __forceinline__ float u16f(unsigned short u){ return __uint_as_float(((unsigned)u)<<16); }
__device__ __forceinline__ float ldany(const void* p, long long i, int f32){
    return f32 ? ((const float*)p)[i] : b2f(((const bf16*)p)[i]);
}

// 2-way bf16 split: x ~= h + m (residual ~2^-17 |x|)
__device__ __forceinline__ void split2(float x, unsigned &h, unsigned &m){
    unsigned u  = __float_as_uint(x);
    unsigned hr = (u + 0x7FFFu + ((u>>16)&1u)) & 0xFFFF0000u;  // RTN-even bf16 (as fp32 bits)
    float xm = x - __uint_as_float(hr);                        // exact (Sterbenz)
    h = hr >> 16;
    m = __float_as_uint(xm) >> 16;                             // truncate
}

// async global->LDS (linear, wave-uniform base + lane*size — staging layout is exactly 16*tid)
__device__ __forceinline__ void gll16(const void* g, void* l){
    __builtin_amdgcn_global_load_lds((const __attribute__((address_space(1))) unsigned*)(g),
                                     (__attribute__((address_space(3))) unsigned*)(l), 16, 0, 0);
}
__device__ __forceinline__ void gll4(const void* g, void* l){
    __builtin_amdgcn_global_load_lds((const __attribute__((address_space(1))) unsigned*)(g),
                                     (__attribute__((address_space(3))) unsigned*)(l), 4, 0, 0);
}

// ---------------------------------------------------------------- param + p canonicalization (+ inline sniff)
struct P20 { const void* p[20]; };

__global__ __launch_bounds__(256) void k_conv(P20 t, const void* __restrict__ p,
                                              const void* __restrict__ x, const void* __restrict__ wq0,
                                              float* __restrict__ prm, float* __restrict__ p32,
                                              int* __restrict__ flags)
{
    __shared__ float red[2][4];
    const unsigned short* xu = (const unsigned short*)x;
    const unsigned short* wu = (const unsigned short*)wq0;
    const int tid = threadIdx.x, lane = tid & 63, wvi = tid >> 6;
    float mx = fabsf(u16f(xu[tid]));
    float mw = fabsf(u16f(wu[tid]));
    for (int off = 32; off; off >>= 1){
        mx = fmaxf(mx, __shfl_down(mx, off));
        mw = fmaxf(mw, __shfl_down(mw, off));
    }
    if (lane == 0){ red[0][wvi] = mx; red[1][wvi] = mw; }
    __syncthreads();
    const float ax = fmaxf(fmaxf(red[0][0], red[0][1]), fmaxf(red[0][2], red[0][3]));
    const float aw = fmaxf(fmaxf(red[1][0], red[1][1]), fmaxf(red[1][2], red[1][3]));
    const int f0 = (ax > 1e6f) ? 1 : 0;   // p/x family is fp32
    const int f1 = (aw > 1e6f) ? 1 : 0;   // weight family is fp32
    if (blockIdx.x == 0 && tid == 0){ flags[0] = f0; flags[1] = f1; }
    const int i = blockIdx.x*256 + tid;
    if (i < NPRM){
        const int sz[20] = {4096,64,4096,64,4096,64,9,3,3,3,192,64,64,64,512,8,8,8,64,8};
        int seg = 0, rem = i;
        while (rem >= sz[seg]){ rem -= sz[seg]; ++seg; }
        prm[i] = ldany(t.p[seg], rem, f1);
    } else {
        const int j = i - NPRM;
        if (j < NPTS*3) p32[j] = ldany(p, j, f0);
    }
}

// ---------------------------------------------------------------- projections (3 waves: Q/K/V; W-cols in regs)
// Wave w owns matrix w: weight column `lane` lives in 64 registers — ZERO LDS traffic.
// FMA order identical to the proven shfl-broadcast sequence => bit-identical xq/xk/xv.
__global__ __launch_bounds__(192) void k_proj(
    const void* __restrict__ x, const int* __restrict__ flags,
    const float* __restrict__ prm,
    float* __restrict__ xq, float* __restrict__ xk, float* __restrict__ xv,
    float* __restrict__ sqk, float* __restrict__ sqv,
    unsigned* __restrict__ hkp, unsigned* __restrict__ mkp,
    unsigned* __restrict__ hvp, unsigned* __restrict__ mvp)
{
    const int tid = threadIdx.x, lane = tid & 63, wvi = tid >> 6;   // wvi in {0,1,2}
    const int f32 = flags[0];
    const int OW = (wvi==0) ? O_WQ : (wvi==1) ? O_WK : O_WV;
    const int OB = (wvi==0) ? O_BQ : (wvi==1) ? O_BK : O_BV;
    float Wc[64];
    #pragma unroll
    for (int k = 0; k < 64; ++k) Wc[k] = prm[OW + k*64 + lane];
    const float bias = prm[OB + lane];
    float* outp = (wvi==0) ? xq : (wvi==1) ? xk : xv;
    const int ptbase = blockIdx.x*32;
    for (int it = 0; it < 32; ++it){
        const int pt = ptbase + it;
        float xl = ldany(x, (long long)pt*64 + lane, f32);
        float acc = bias;
        #pragma unroll
        for (int k = 0; k < 64; ++k) acc += __shfl(xl, k)*Wc[k];
        outp[(size_t)pt*64 + lane] = acc;
        if (wvi){
            unsigned h16, m16; split2(acc, h16, m16);
            unsigned hn = __shfl_down(h16,1), mn = __shfl_down(m16,1);
            if (!(lane & 1)){
                const int u = lane >> 3, pos = u ^ (pt & 7);
                const size_t gi = (size_t)pt*32 + pos*4 + ((lane & 7) >> 1);
                if (wvi == 1){ hkp[gi] = h16 | (hn<<16);  mkp[gi] = m16 | (mn<<16); }
                else         { hvp[gi] = h16 | (hn<<16);  mvp[gi] = m16 | (mn<<16); }
            }
            float s = acc*acc;
            for (int off=32; off; off>>=1) s += __shfl_down(s, off);
            if (lane == 0){ if (wvi == 1) sqk[pt] = s; else sqv[pt] = s; }
        }
    }
}

// ---------------------------------------------------------------- KNN (MFMA prune + exact re-rank + fused BN1)
// grid 1024 (XCD-swizzled). Block: 64 queries vs ALL 4096 cands (64 chunks).
// Round-8 schedule: Dt is WAVE-PRIVATE (MFMA writes / selection reads the same wv-rows),
// so per chunk: MFMA -> barrier(all done reading planes) -> async global_load_lds stage of
// chunk n+1 (linear 16*tid copy, no VGPR round-trip) -> selection (hides load latency)
// -> barrier (vmcnt drained => planes n+1 ready). Selection/rerank arithmetic unchanged.

using bfrag  = __attribute__((ext_vector_type(8))) short;   // 8 x bf16 (4 VGPRs)
using f32x4v = __attribute__((ext_vector_type(4))) float;   // MFMA accumulator

// swizzled LDS address (in shorts): row stride 64 shorts (128B), 16B units XOR'd by row&7
__device__ __forceinline__ int lds_sw(int row, int unit){
    return (row<<6) + (((unit ^ row) & 7)<<3);
}

__global__ __launch_bounds__(256, 4) void k_knn_part(
    const float* __restrict__ featk, const float* __restrict__ featv,
    const unsigned* __restrict__ hkp, const unsigned* __restrict__ mkp,
    const unsigned* __restrict__ hvp, const unsigned* __restrict__ mvp,
    const float* __restrict__ sqk, const float* __restrict__ sqv,
    const float* __restrict__ p32, const float* __restrict__ prm,
    int* __restrict__ idx_k, int* __restrict__ idx_v,
    float* __restrict__ part1)
{
    __shared__ __attribute__((aligned(16))) unsigned char smem[34048];
    __shared__ float bn1red[4][6];
    unsigned short* Ch = (unsigned short*)smem;                 // 8KB h-plane tile (swizzled)
    unsigned short* Cm = (unsigned short*)(smem + 8192);        // 8KB m-plane tile
    float* Dt  = (float*)(smem + 16384);                        // 64x68 dist tile (17408B)
    float* sqC = (float*)(smem + 16384 + 17408);                // 256B
    unsigned long long* Lbuf = (unsigned long long*)smem;       // tail overlay (256*6*8=12288B)

    const int tid = threadIdx.x;
    // XCD-aware swizzle: 1024 blocks = 8 XCDs x 128 contiguous logicals
    const int swz = ((int)blockIdx.x & 7) * 128 + ((int)blockIdx.x >> 3);
    const int kid = swz >> 9;
    const int bid = swz & 511;
    const float*    feat = kid ? featv : featk;
    const float*    sq   = kid ? sqv  : sqk;
    const unsigned* hpl  = kid ? hvp : hkp;
    const unsigned* mpl  = kid ? mvp : mkp;
    const int b  = bid >> 6;
    const int qt = bid & 63;
    const int q0 = b*NPB + qt*64;
    const int cb = b*NPB;

    const int lane = tid & 63, wv = tid >> 6;
    const int lq = lane & 15, lg = lane >> 4;        // MFMA fragment lane coords
    const int selq = (wv << 4) + (lane >> 2);        // selection row (0..63) — wave-private rows
    const int sub  = lane & 3;
    const int owner = lane & ~3;

    // ---- Q fragments from planes (register-resident, 2 planes x 2 k-steps)
    bfrag qh[2], qm[2];
    {
        const int qr = q0 + (wv<<4) + lq;
        #pragma unroll
        for (int ks = 0; ks < 2; ++ks){
            const int u0 = ks*4 + lg;
            const int pos = u0 ^ (qr & 7);
            union { uint4 u; bfrag v; } ch, cm;
            ch.u = *(const uint4*)&hpl[(size_t)qr*32 + pos*4];
            cm.u = *(const uint4*)&mpl[(size_t)qr*32 + pos*4];
            qh[ks] = ch.v; qm[ks] = cm.v;
        }
    }

    // distributed top-20: 5 sorted entries per sub-lane (ranks sub*5 .. sub*5+4)
    float d5[5]; int i5[5];
    #pragma unroll
    for (int i=0;i<5;++i){ d5[i] = 3.4e38f; i5[i] = 0; }

    // staging base: global offset 16*tid bytes, LDS offset 16*tid bytes (linear copy)
    const unsigned* hrowA = hpl + (size_t)cb*32 + (size_t)tid*4;
    const unsigned* mrowA = mpl + (size_t)cb*32 + (size_t)tid*4;

    #define STAGE(CHN) { \
        const size_t co = (size_t)(CHN)*2048; \
        gll16(hrowA + co,        (void*)&Ch[8*tid]); \
        gll16(hrowA + co + 1024, (void*)&Ch[8*tid + 2048]); \
        gll16(mrowA + co,        (void*)&Cm[8*tid]); \
        gll16(mrowA + co + 1024, (void*)&Cm[8*tid + 2048]); \
        if (tid < 64) gll4(sq + cb + (CHN)*64 + tid, (void*)&sqC[tid]); \
    }

    #define MFMA_PHASE() { \
        _Pragma("unroll") \
        for (int ct = 0; ct < 4; ++ct){ \
            const int cd = ct*16 + lq; \
            union { uint4 u; bfrag v; } bh0u, bh1u, bm0u, bm1u; \
            bh0u.u = *(const uint4*)&Ch[lds_sw(cd, lg)]; \
            bh1u.u = *(const uint4*)&Ch[lds_sw(cd, 4+lg)]; \
            bm0u.u = *(const uint4*)&Cm[lds_sw(cd, lg)]; \
            bm1u.u = *(const uint4*)&Cm[lds_sw(cd, 4+lg)]; \
            f32x4v a = {0.f, 0.f, 0.f, 0.f}; \
            a = __builtin_amdgcn_mfma_f32_16x16x32_bf16(qm[0], bm0u.v, a, 0, 0, 0); \
            a = __builtin_amdgcn_mfma_f32_16x16x32_bf16(qm[1], bm1u.v, a, 0, 0, 0); \
            a = __builtin_amdgcn_mfma_f32_16x16x32_bf16(qh[0], bm0u.v, a, 0, 0, 0); \
            a = __builtin_amdgcn_mfma_f32_16x16x32_bf16(qm[0], bh0u.v, a, 0, 0, 0); \
            a = __builtin_amdgcn_mfma_f32_16x16x32_bf16(qh[1], bm1u.v, a, 0, 0, 0); \
            a = __builtin_amdgcn_mfma_f32_16x16x32_bf16(qm[1], bh1u.v, a, 0, 0, 0); \
            a = __builtin_amdgcn_mfma_f32_16x16x32_bf16(qh[0], bh0u.v, a, 0, 0, 0); \
            a = __builtin_amdgcn_mfma_f32_16x16x32_bf16(qh[1], bh1u.v, a, 0, 0, 0); \
            const float sc = sqC[ct*16 + lq]; \
            _Pragma("unroll") \
            for (int r = 0; r < 4; ++r) \
                Dt[((wv<<4) + (lg<<2) + r)*68 + ct*16 + lq] = sc - 2.f*a[r]; \
        } }

    // prologue: async-stage chunk 0
    STAGE(0)
    __syncthreads();

    for (int chn = 0; chn < 64; ++chn){
        MFMA_PHASE()                       // planes(chn) -> Dt (own wave rows)
        __syncthreads();                   // all waves done READING planes(chn)
        if (chn + 1 < 64) STAGE(chn+1)     // async loads into planes; latency hidden by selection
        // ---- cooperative distributed selection on Dt(chn) (own wave rows)
        {
            float worst = __shfl(d5[4], owner+3);     // global rank-19 value
            unsigned m16 = 0;
            const int rowoff = selq*68 + sub*16;
            #pragma unroll
            for (int r = 0; r < 4; ++r){
                float4 v = *(const float4*)&Dt[rowoff + 4*r];
                m16 |= (v.x < worst ? 1u : 0u) << (4*r+0);
                m16 |= (v.y < worst ? 1u : 0u) << (4*r+1);
                m16 |= (v.z < worst ? 1u : 0u) << (4*r+2);
                m16 |= (v.w < worst ? 1u : 0u) << (4*r+3);
            }
            unsigned ma = __shfl(m16, owner+0), mb = __shfl(m16, owner+1);
            unsigned mc = __shfl(m16, owner+2), md = __shfl(m16, owner+3);
            unsigned long long m = (unsigned long long)ma
                                 | ((unsigned long long)mb << 16)
                                 | ((unsigned long long)mc << 32)
                                 | ((unsigned long long)md << 48);
            const int qrow = selq*68;
            const int c0 = cb + chn*64;
            const int prevlane = (lane - 1) & 63;
            while (m){
                int c = (int)__builtin_ctzll(m); m &= m - 1;
                float d = Dt[qrow + c];
                int gi = c0 + c;
                float pl = __shfl(d5[4], prevlane);
                int   pi = __shfl(i5[4], prevlane);
                bool takePrev = (sub != 0) && (pl > d);
                float v  = takePrev ? pl : d;
                int   vi = takePrev ? pi : gi;
                #pragma unroll
                for (int i = 4; i >= 1; --i){
                    bool sh   = d5[i-1] > v;
                    bool here = !sh && (d5[i] > v);
                    d5[i] = sh ? d5[i-1] : (here ? v  : d5[i]);
                    i5[i] = sh ? i5[i-1] : (here ? vi : i5[i]);
                }
                bool h0 = d5[0] > v;
                d5[0] = h0 ? v  : d5[0];
                i5[0] = h0 ? vi : i5[0];
            }
        }
        __syncthreads();                   // vmcnt drained => planes(chn+1) ready
    }
    #undef MFMA_PHASE
    #undef STAGE

    // ---- tail: each lane exact-recomputes its own 5 survivors
    // exact VALU distance — IDENTICAL arithmetic to the proven round-3 code
    unsigned long long k5[5];
    {
        const float* qrow = feat + (size_t)(q0 + selq)*64;
        #pragma unroll
        for (int s = 0; s < 5; ++s){
            const int gi = i5[s];
            const float* crow = feat + (size_t)gi*64;
            float acc = 0.f;
            #pragma unroll
            for (int k4 = 0; k4 < 16; ++k4){
                float4 qv = *(const float4*)&qrow[4*k4];
                float4 cv = *(const float4*)&crow[4*k4];
                acc += qv.x*cv.x; acc += qv.y*cv.y; acc += qv.z*cv.z; acc += qv.w*cv.w;
            }
            float d = sq[gi] - 2.f*acc;
            unsigned ud = __float_as_uint(d);
            ud ^= (ud & 0x80000000u) ? 0xFFFFFFFFu : 0x80000000u;   // order-preserving map
            k5[s] = ((unsigned long long)ud << 32) | (unsigned)gi;  // (d, idx) lexicographic
        }
    }
    // static odd-even sort of 5 keys
    #pragma unroll
    for (int pass = 0; pass < 5; ++pass){
        #pragma unroll
        for (int i = (pass & 1); i + 1 < 5; i += 2){
            unsigned long long a = k5[i], bb = k5[i+1];
            bool sw = a > bb;
            k5[i]   = sw ? bb : a;
            k5[i+1] = sw ? a : bb;
        }
    }
    __syncthreads();   // smem reuse: planes/Dt dead
    #pragma unroll
    for (int j = 0; j < 5; ++j) Lbuf[(size_t)tid*6 + j] = k5[j];
    Lbuf[(size_t)tid*6 + 5] = ~0ull;   // sentinel
    __syncthreads();
    int fi[16];
    #pragma unroll
    for (int i = 0; i < 16; ++i) fi[i] = 0;
    if (sub == 0){
        const unsigned long long* L0 = &Lbuf[(size_t)(tid+0)*6];
        const unsigned long long* L1 = &Lbuf[(size_t)(tid+1)*6];
        const unsigned long long* L2 = &Lbuf[(size_t)(tid+2)*6];
        const unsigned long long* L3 = &Lbuf[(size_t)(tid+3)*6];
        int p0 = 0, p1 = 0, p2 = 0, p3 = 0;
        #pragma unroll
        for (int o = 0; o < 16; ++o){
            unsigned long long b0 = L0[p0], b1v = L1[p1], b2v = L2[p2], b3v = L3[p3];
            unsigned long long m01 = (b0  < b1v) ? b0  : b1v;  int s01 = (b0  < b1v) ? 0 : 1;
            unsigned long long m23 = (b2v < b3v) ? b2v : b3v;  int s23 = (b2v < b3v) ? 2 : 3;
            unsigned long long mm  = (m01 < m23) ? m01 : m23;  int ss  = (m01 < m23) ? s01 : s23;
            fi[o] = (int)(unsigned)(mm & 0xFFFFFFFFull);
            if      (ss == 0) ++p0;
            else if (ss == 1) ++p1;
            else if (ss == 2) ++p2;
            else              ++p3;
        }
        int* idx_out = kid ? idx_v : idx_k;
        #pragma unroll
        for (int i4 = 0; i4 < 4; ++i4)
            *(int4*)&idx_out[(size_t)(q0+selq)*16 + 4*i4] =
                make_int4(fi[4*i4], fi[4*i4+1], fi[4*i4+2], fi[4*i4+3]);
    }

    // ---- fused BN1 partial stats (kid==0 blocks): h = p_rel @ wp1 + bp1 over block's
    // 64 queries x 16 neighbors; 4 neighbors per sub-lane; full-wave butterfly reduce.
    if (kid == 0){
        const float w00=prm[O_WP1+0], w01=prm[O_WP1+1], w02=prm[O_WP1+2];
        const float w10=prm[O_WP1+3], w11=prm[O_WP1+4], w12=prm[O_WP1+5];
        const float w20=prm[O_WP1+6], w21=prm[O_WP1+7], w22=prm[O_WP1+8];
        const float bb0=prm[O_BP1+0], bb1=prm[O_BP1+1], bb2=prm[O_BP1+2];
        const size_t gq = (size_t)(q0 + selq);
        const float px=p32[gq*3+0], py=p32[gq*3+1], pz=p32[gq*3+2];
        float s0=0.f,s1=0.f,s2=0.f,t0=0.f,t1=0.f,t2=0.f;
        #pragma unroll
        for (int o = 0; o < 16; ++o){
            int gi = __shfl(fi[o], owner);
            if ((o & 3) == sub){
                const int j = gi & IMASK;
                float rx = p32[j*3+0]-px, ry = p32[j*3+1]-py, rz = p32[j*3+2]-pz;
                float h0 = bb0 + rx*w00 + ry*w10 + rz*w20;
                float h1 = bb1 + rx*w01 + ry*w11 + rz*w21;
                float h2 = bb2 + rx*w02 + ry*w12 + rz*w22;
                s0+=h0; s1+=h1; s2+=h2; t0+=h0*h0; t1+=h1*h1; t2+=h2*h2;
            }
        }
        #pragma unroll
        for (int off = 1; off < 64; off <<= 1){
            s0+=__shfl_down(s0,off); s1+=__shfl_down(s1,off); s2+=__shfl_down(s2,off);
            t0+=__shfl_down(t0,off); t1+=__shfl_down(t1,off); t2+=__shfl_down(t2,off);
        }
        if (lane == 0){
            bn1red[wv][0]=s0; bn1red[wv][1]=s1; bn1red[wv][2]=s2;
            bn1red[wv][3]=t0; bn1red[wv][4]=t1; bn1red[wv][5]=t2;
        }
        __syncthreads();
        if (tid < 6)
            part1[(size_t)tid*512 + bid] =
                bn1red[0][tid]+bn1red[1][tid]+bn1red[2][tid]+bn1red[3][tid];
    }
}

// ---------------------------------------------------------------- BN reduce (parallel, transposed part[S][G])
// grid = C blocks; block c reduces channels c (sum) and C+c (sumsq), writes aff.
__global__ __launch_bounds__(256) void k_bnred_par(
    const float* __restrict__ part, int G, int C,
    const float* __restrict__ gamma, const float* __restrict__ beta,
    float* __restrict__ aff, float invCount)
{
    __shared__ float rs[4], rq[4];
    const int c = blockIdx.x;
    const int tid = threadIdx.x;
    float s = 0.f, q = 0.f;
    for (int g = tid; g < G; g += 256){
        s += part[(size_t)c*G + g];
        q += part[(size_t)(C+c)*G + g];
    }
    for (int off=32; off; off>>=1){ s += __shfl_down(s,off); q += __shfl_down(q,off); }
    if ((tid & 63) == 0){ rs[tid>>6] = s; rq[tid>>6] = q; }
    __syncthreads();
    if (tid == 0){
        float S = rs[0]+rs[1]+rs[2]+rs[3], Q = rq[0]+rq[1]+rq[2]+rq[3];
        float mean = S*invCount;
        float var  = fmaxf(Q*invCount - mean*mean, 0.f);
        float sc = gamma[c] * rsqrtf(var + EPSB);
        aff[c]   = sc;
        aff[C+c] = beta[c] - mean*sc;
    }
}

// ---------------------------------------------------------------- BN2 stats over r (unrolled x4)
__global__ __launch_bounds__(256) void k_rstats(
    const float* __restrict__ p32,
    const float* __restrict__ xq, const float* __restrict__ xk, const int* __restrict__ idx_k,
    const float* __restrict__ bn1aff, const float* __restrict__ prm,
    float* __restrict__ part2)
{
    const int tid = threadIdx.x, lane = tid & 63, wvi = tid >> 6;
    const float wa = prm[O_WP2+lane], wb = prm[O_WP2+64+lane], wc = prm[O_WP2+128+lane];
    const float bpc = prm[O_BP2+lane];
    const float w00=prm[O_WP1+0], w01=prm[O_WP1+1], w02=prm[O_WP1+2];
    const float w10=prm[O_WP1+3], w11=prm[O_WP1+4], w12=prm[O_WP1+5];
    const float w20=prm[O_WP1+6], w21=prm[O_WP1+7], w22=prm[O_WP1+8];
    const float bb0=prm[O_BP1+0], bb1=prm[O_BP1+1], bb2=prm[O_BP1+2];
    const float sc0=bn1aff[0], sc1=bn1aff[1], sc2=bn1aff[2];
    const float sh0=bn1aff[3], sh1=bn1aff[4], sh2=bn1aff[5];
    const int base = (blockIdx.x*4 + wvi) * 64;
    float asum=0.f, asq=0.f;
    float px=0.f, py=0.f, pz=0.f, xql=0.f;
    for (int e4 = 0; e4 < 16; ++e4){
        const int gb = base + e4*4;
        if ((gb & 15) == 0){
            const int n = gb >> 4;
            px=p32[n*3+0]; py=p32[n*3+1]; pz=p32[n*3+2];
            xql = xq[(size_t)n*64+lane];
        }
        int4 jj = *(const int4*)&idx_k[gb];
        int j[4] = { jj.x & IMASK, jj.y & IMASK, jj.z & IMASK, jj.w & IMASK };
        float kx[4], qx[4][3];
        #pragma unroll
        for (int u=0;u<4;++u){
            qx[u][0]=p32[j[u]*3+0]; qx[u][1]=p32[j[u]*3+1]; qx[u][2]=p32[j[u]*3+2];
            kx[u] = xk[(size_t)j[u]*64+lane];
        }
        #pragma unroll
        for (int u=0;u<4;++u){
            float rx = qx[u][0]-px, ry = qx[u][1]-py, rz = qx[u][2]-pz;
            float h0 = bb0 + rx*w00 + ry*w10 + rz*w20;
            float h1 = bb1 + rx*w01 + ry*w11 + rz*w21;
            float h2 = bb2 + rx*w02 + ry*w12 + rz*w22;
            float r0 = fmaxf(h0*sc0+sh0, 0.f), r1 = fmaxf(h1*sc1+sh1,0.f), r2 = fmaxf(h2*sc2+sh2,0.f);
            float pr = r0*wa + r1*wb + r2*wc + bpc;
            float rv = kx[u] - xql + pr;
            asum += rv; asq += rv*rv;
        }
    }
    __shared__ float red[4][128];
    red[wvi][lane] = asum; red[wvi][64+lane] = asq;
    __syncthreads();
    if (tid < 128)
        part2[(size_t)tid*2048 + blockIdx.x] = red[0][tid]+red[1][tid]+red[2][tid]+red[3][tid];
}

// ---------------------------------------------------------------- BN3 stats over w (+ wbuf store)
__global__ __launch_bounds__(256) void k_wstats(
    const float* __restrict__ p32,
    const float* __restrict__ xq, const float* __restrict__ xk, const int* __restrict__ idx_k,
    const float* __restrict__ bn1aff, const float* __restrict__ prm,
    const float* __restrict__ bn2aff, float* __restrict__ wbuf, float* __restrict__ part3)
{
    __shared__ float4 PRW[64];
    __shared__ float2 SS2[64];
    __shared__ float4 W1A[64], W1B[64];
    const int tid = threadIdx.x;
    if (tid < 64){
        PRW[tid] = make_float4(prm[O_WP2+tid], prm[O_WP2+64+tid], prm[O_WP2+128+tid], prm[O_BP2+tid]);
        SS2[tid] = make_float2(bn2aff[tid], bn2aff[64+tid]);
        W1A[tid] = make_float4(prm[O_WW1+tid*8+0],prm[O_WW1+tid*8+1],prm[O_WW1+tid*8+2],prm[O_WW1+tid*8+3]);
        W1B[tid] = make_float4(prm[O_WW1+tid*8+4],prm[O_WW1+tid*8+5],prm[O_WW1+tid*8+6],prm[O_WW1+tid*8+7]);
    }
    __syncthreads();
    const int g = blockIdx.x*256 + tid;
    const int n = g >> 4;
    const int j = idx_k[g] & IMASK;
    const float w00=prm[O_WP1+0], w01=prm[O_WP1+1], w02=prm[O_WP1+2];
    const float w10=prm[O_WP1+3], w11=prm[O_WP1+4], w12=prm[O_WP1+5];
    const float w20=prm[O_WP1+6], w21=prm[O_WP1+7], w22=prm[O_WP1+8];
    const float bb0=prm[O_BP1+0], bb1=prm[O_BP1+1], bb2=prm[O_BP1+2];
    const float sc0=bn1aff[0], sc1=bn1aff[1], sc2=bn1aff[2];
    const float sh0=bn1aff[3], sh1=bn1aff[4], sh2=bn1aff[5];
    float rx = p32[j*3+0] - p32[n*3+0];
    float ry = p32[j*3+1] - p32[n*3+1];
    float rz = p32[j*3+2] - p32[n*3+2];
    float h0 = bb0 + rx*w00 + ry*w10 + rz*w20;
    float h1 = bb1 + rx*w01 + ry*w11 + rz*w21;
    float h2 = bb2 + rx*w02 + ry*w12 + rz*w22;
    float r0 = fmaxf(h0*sc0+sh0, 0.f), r1 = fmaxf(h1*sc1+sh1,0.f), r2 = fmaxf(h2*sc2+sh2,0.f);
    float wacc[8];
    #pragma unroll
    for (int i=0;i<8;++i) wacc[i] = prm[O_BW1+i];
    const float4* kr = (const float4*)(xk + (size_t)j*64);
    const float4* qr = (const float4*)(xq + (size_t)n*64);
    #pragma unroll
    for (int c4=0;c4<16;++c4){
        float4 kv = kr[c4], qv = qr[c4];
        float kvv[4] = {kv.x,kv.y,kv.z,kv.w};
        float qvv[4] = {qv.x,qv.y,qv.z,qv.w};
        #pragma unroll
        for (int d=0; d<4; ++d){
            int c = 4*c4 + d;
            float4 pw = PRW[c]; float2 ss = SS2[c];
            float pr = r0*pw.x + r1*pw.y + r2*pw.z + pw.w;
            float rr = kvv[d] - qvv[d] + pr;
            float y = fmaxf(rr*ss.x + ss.y, 0.f);
            float4 wA = W1A[c], wB = W1B[c];
            wacc[0]+=y*wA.x; wacc[1]+=y*wA.y; wacc[2]+=y*wA.z; wacc[3]+=y*wA.w;
            wacc[4]+=y*wB.x; wacc[5]+=y*wB.y; wacc[6]+=y*wB.z; wacc[7]+=y*wB.w;
        }
    }
    *(float4*)&wbuf[(size_t)g*8]   = make_float4(wacc[0],wacc[1],wacc[2],wacc[3]);
    *(float4*)&wbuf[(size_t)g*8+4] = make_float4(wacc[4],wacc[5],wacc[6],wacc[7]);
    float st[16];
    #pragma unroll
    for (int i=0;i<8;++i){ st[i]=wacc[i]; st[8+i]=wacc[i]*wacc[i]; }
    for (int off=32; off; off>>=1){
        #pragma unroll
        for (int k=0;k<16;++k) st[k] += __shfl_down(st[k], off);
    }
    __shared__ float red[4][16];
    const int lane = tid&63, wvi = tid>>6;
    if (lane==0){
        #pragma unroll
        for (int k=0;k<16;++k) red[wvi][k]=st[k];
    }
    __syncthreads();
    if (tid < 16)
        part3[(size_t)tid*2048 + blockIdx.x] = red[0][tid]+red[1][tid]+red[2][tid]+red[3][tid];
}

// ---------------------------------------------------------------- final (reads wbuf; no shfl chain)
__global__ __launch_bounds__(256) void k_out(
    const float* __restrict__ p32, const float* __restrict__ xv,
    const int* __restrict__ idx_k, const int* __restrict__ idx_v,
    const float* __restrict__ bn1aff, const float* __restrict__ prm,
    const float* __restrict__ wbuf, const float* __restrict__ bn3aff,
    const int* __restrict__ flags, void* __restrict__ out)
{
    const int tid = threadIdx.x, lane = tid & 63, wvi = tid >> 6;
    const int n = blockIdx.x*4 + wvi;
    const int f32 = flags[0];
    const float w00=prm[O_WP1+0], w01=prm[O_WP1+1], w02=prm[O_WP1+2];
    const float w10=prm[O_WP1+3], w11=prm[O_WP1+4], w12=prm[O_WP1+5];
    const float w20=prm[O_WP1+6], w21=prm[O_WP1+7], w22=prm[O_WP1+8];
    const float bb0=prm[O_BP1+0], bb1=prm[O_BP1+1], bb2=prm[O_BP1+2];
    const float sc0=bn1aff[0], sc1=bn1aff[1], sc2=bn1aff[2];
    const float sh0=bn1aff[3], sh1=bn1aff[4], sh2=bn1aff[5];
    const float wa=prm[O_WP2+lane], wb=prm[O_WP2+64+lane], wc=prm[O_WP2+128+lane];
    const float bpc=prm[O_BP2+lane];
    const int i = lane & 7;
    float s3[8], t3[8], w2col[8];
    #pragma unroll
    for (int m=0;m<8;++m){
        s3[m]=bn3aff[m]; t3[m]=bn3aff[8+m];
        w2col[m]=prm[O_WW2+m*8+i];
    }
    const float bw2i = prm[O_BW2+i];
    const float px=p32[n*3+0], py=p32[n*3+1], pz=p32[n*3+2];
    float comb[16], wf[16];
    #pragma unroll
    for (int t=0;t<16;++t){
        const int g = n*16 + t;
        const int jk = idx_k[g] & IMASK;
        const int jv = idx_v[g] & IMASK;
        float rx=p32[jk*3+0]-px, ry=p32[jk*3+1]-py, rz=p32[jk*3+2]-pz;
        float h0=bb0+rx*w00+ry*w10+rz*w20;
        float h1=bb1+rx*w01+ry*w11+rz*w21;
        float h2=bb2+rx*w02+ry*w12+rz*w22;
        float r0=fmaxf(h0*sc0+sh0,0.f), r1=fmaxf(h1*sc1+sh1,0.f), r2=fmaxf(h2*sc2+sh2,0.f);
        float pr=r0*wa+r1*wb+r2*wc+bpc;
        float4 wA = *(const float4*)&wbuf[(size_t)g*8];
        float4 wB = *(const float4*)&wbuf[(size_t)g*8+4];
        float wm[8] = {wA.x,wA.y,wA.z,wA.w,wB.x,wB.y,wB.z,wB.w};
        float acc = bw2i;
        #pragma unroll
        for (int m=0;m<8;++m){
            float y3 = fmaxf(wm[m]*s3[m]+t3[m],0.f);
            acc += y3*w2col[m];
        }
        wf[t]=acc;
        comb[t]=xv[(size_t)jv*64+lane]+pr;
    }
    float mx = wf[0];
    #pragma unroll
    for (int t=1;t<16;++t) mx = fmaxf(mx, wf[t]);
    float ssum=0.f, osum=0.f;
    #pragma unroll
    for (int t=0;t<16;++t){ float e = __expf(wf[t]-mx); ssum += e; osum += e*comb[t]; }
    const float v = osum / ssum;
    if (f32) ((float*)out)[(size_t)n*64+lane] = v;
    else     ((bf16*)out)[(size_t)n*64+lane] = __float2bfloat16(v);
}

// ---------------------------------------------------------------- launcher
extern "C" void kernel_launch(void* const* d_in, const int* in_sizes, int n_in,
                              void* d_out, int out_size, void* d_ws, size_t ws_size,
                              hipStream_t stream)
{
    const void* p  = d_in[0];
    const void* x  = d_in[1];
    P20 prms;
    for (int i = 0; i < 20; ++i) prms.p[i] = d_in[3+i];

    // workspace layout (floats) — within the 48.08 MB proven footprint
    float* W = (float*)d_ws;
    float* xqf    = W + 0;
    float* xkf    = W + 2097152;
    float* xvf    = W + 4194304;
    float* sqk    = W + 6291456;
    float* sqv    = W + 6324224;
    int*   idx_k  = (int*)(W + 6356992);
    int*   idx_v  = (int*)(W + 6881280);
    float* p32    = W + 7405568;   // 98304
    float* prm    = W + 7503872;   // 13490 (+pad)
    float* part1  = W + 7517376;   // transposed [6][512] = 3072 (slot 12288)
    float* part2  = W + 7529664;   // transposed [128][2048] = 262144
    float* part3  = W + 7791808;   // transposed [16][2048] = 32768
    float* bn1aff = W + 7824576;   // 16
    float* bn2aff = W + 7824592;   // 128
    float* bn3aff = W + 7824720;   // 16
    int*   flags  = (int*)(W + 7824736); // 2 (+pad to 16)
    // overlay region (4,194,304 floats): bf16 h/m planes (live: k_proj -> k_knn_part),
    // then wbuf (written k_wstats, read k_out) — disjoint lifetimes.
    unsigned* hkp = (unsigned*)(W + 7824752);             // 1,048,576 u32
    unsigned* mkp = (unsigned*)(W + 7824752 + 1048576);
    unsigned* hvp = (unsigned*)(W + 7824752 + 2097152);
    unsigned* mvp = (unsigned*)(W + 7824752 + 3145728);
    float* wbuf   = W + 7824752;   // 4,194,304

    const float invP = 1.f / (float)NPAIR;

    k_conv<<<(NPRM + NPTS*3 + 255)/256,256,0,stream>>>(prms, p, x, d_in[3], prm, p32, flags);
    k_proj<<<1024,192,0,stream>>>(x, flags, prm, xqf,xkf,xvf, sqk,sqv, hkp,mkp,hvp,mvp);
    k_knn_part<<<1024,256,0,stream>>>(xkf, xvf, hkp,mkp,hvp,mvp, sqk, sqv,
                                      p32, prm, idx_k, idx_v, part1);
    k_bnred_par<<<3,256,0,stream>>>(part1, 512, 3, prm+O_GP, prm+O_BTP, bn1aff, invP);
    k_rstats<<<2048,256,0,stream>>>(p32, xqf, xkf, idx_k, bn1aff, prm, part2);
    k_bnred_par<<<64,256,0,stream>>>(part2, 2048, 64, prm+O_G1, prm+O_BT1, bn2aff, invP);
    k_wstats<<<2048,256,0,stream>>>(p32, xqf, xkf, idx_k, bn1aff, prm, bn2aff, wbuf, part3);
    k_bnred_par<<<8,256,0,stream>>>(part3, 2048, 8, prm+O_G2, prm+O_BT2, bn3aff, invP);
    k_out<<<8192,256,0,stream>>>(p32, xvf, idx_k, idx_v, bn1aff, prm,
                                 wbuf, bn3aff, flags, d_out);
}

// Round 9
// 591.861 us; speedup vs baseline: 1.0374x; 1.0374x over previous
//
#include <hip/hip_runtime.h>
#include <hip/hip_bf16.h>

typedef __hip_bfloat16 bf16;

#define NPTS  32768
#define NPB   4096
#define NPAIR (NPTS*16)
#define IMASK 32767
#define EPSB  1e-5f

// packed fp32 param-block offsets (floats)
#define O_WQ  0
#define O_BQ  4096
#define O_WK  4160
#define O_BK  8256
#define O_WV  8320
#define O_BV  12416
#define O_WP1 12480
#define O_BP1 12489
#define O_GP  12492
#define O_BTP 12495
#define O_WP2 12498
#define O_BP2 12690
#define O_G1  12754
#define O_BT1 12818
#define O_WW1 12882
#define O_BW1 13394
#define O_G2  13402
#define O_BT2 13410
#define O_WW2 13418
#define O_BW2 13482
#define NPRM  13490

__device__ __forceinline__ float b2f(bf16 v){ return __bfloat162float(v); }
__device__ __forceinline__ float u16f(unsigned short u){ return __uint_as_float(((unsigned)u)<<16); }
__device__ __forceinline__ float ldany(const void* p, long long i, int f32){
    return f32 ? ((const float*)p)[i] : b2f(((const bf16*)p)[i]);
}

// 2-way bf16 split: x ~= h + m (residual ~2^-17 |x|)
__device__ __forceinline__ void split2(float x, unsigned &h, unsigned &m){
    unsigned u  = __float_as_uint(x);
    unsigned hr = (u + 0x7FFFu + ((u>>16)&1u)) & 0xFFFF0000u;  // RTN-even bf16 (as fp32 bits)
    float xm = x - __uint_as_float(hr);                        // exact (Sterbenz)
    h = hr >> 16;
    m = __float_as_uint(xm) >> 16;                             // truncate
}

// async global->LDS (linear, wave-uniform base + lane*size — staging layout is exactly 16*tid)
__device__ __forceinline__ void gll16(const void* g, void* l){
    __builtin_amdgcn_global_load_lds((const __attribute__((address_space(1))) unsigned*)(g),
                                     (__attribute__((address_space(3))) unsigned*)(l), 16, 0, 0);
}
__device__ __forceinline__ void gll4(const void* g, void* l){
    __builtin_amdgcn_global_load_lds((const __attribute__((address_space(1))) unsigned*)(g),
                                     (__attribute__((address_space(3))) unsigned*)(l), 4, 0, 0);
}

// ---------------------------------------------------------------- param + p canonicalization (+ inline sniff)
struct P20 { const void* p[20]; };

__global__ __launch_bounds__(256) void k_conv(P20 t, const void* __restrict__ p,
                                              const void* __restrict__ x, const void* __restrict__ wq0,
                                              float* __restrict__ prm, float* __restrict__ p32,
                                              int* __restrict__ flags)
{
    __shared__ float red[2][4];
    const unsigned short* xu = (const unsigned short*)x;
    const unsigned short* wu = (const unsigned short*)wq0;
    const int tid = threadIdx.x, lane = tid & 63, wvi = tid >> 6;
    float mx = fabsf(u16f(xu[tid]));
    float mw = fabsf(u16f(wu[tid]));
    for (int off = 32; off; off >>= 1){
        mx = fmaxf(mx, __shfl_down(mx, off));
        mw = fmaxf(mw, __shfl_down(mw, off));
    }
    if (lane == 0){ red[0][wvi] = mx; red[1][wvi] = mw; }
    __syncthreads();
    const float ax = fmaxf(fmaxf(red[0][0], red[0][1]), fmaxf(red[0][2], red[0][3]));
    const float aw = fmaxf(fmaxf(red[1][0], red[1][1]), fmaxf(red[1][2], red[1][3]));
    const int f0 = (ax > 1e6f) ? 1 : 0;   // p/x family is fp32
    const int f1 = (aw > 1e6f) ? 1 : 0;   // weight family is fp32
    if (blockIdx.x == 0 && tid == 0){ flags[0] = f0; flags[1] = f1; }
    const int i = blockIdx.x*256 + tid;
    if (i < NPRM){
        const int sz[20] = {4096,64,4096,64,4096,64,9,3,3,3,192,64,64,64,512,8,8,8,64,8};
        int seg = 0, rem = i;
        while (rem >= sz[seg]){ rem -= sz[seg]; ++seg; }
        prm[i] = ldany(t.p[seg], rem, f1);
    } else {
        const int j = i - NPRM;
        if (j < NPTS*3) p32[j] = ldany(p, j, f0);
    }
}

// ---------------------------------------------------------------- projections (3 waves: Q/K/V; W-cols in regs)
// Wave w owns matrix w: weight column `lane` lives in 64 registers — ZERO LDS traffic.
// FMA order identical to the proven shfl-broadcast sequence => bit-identical xq/xk/xv.
__global__ __launch_bounds__(192) void k_proj(
    const void* __restrict__ x, const int* __restrict__ flags,
    const float* __restrict__ prm,
    float* __restrict__ xq, float* __restrict__ xk, float* __restrict__ xv,
    float* __restrict__ sqk, float* __restrict__ sqv,
    unsigned* __restrict__ hkp, unsigned* __restrict__ mkp,
    unsigned* __restrict__ hvp, unsigned* __restrict__ mvp)
{
    const int tid = threadIdx.x, lane = tid & 63, wvi = tid >> 6;   // wvi in {0,1,2}
    const int f32 = flags[0];
    const int OW = (wvi==0) ? O_WQ : (wvi==1) ? O_WK : O_WV;
    const int OB = (wvi==0) ? O_BQ : (wvi==1) ? O_BK : O_BV;
    float Wc[64];
    #pragma unroll
    for (int k = 0; k < 64; ++k) Wc[k] = prm[OW + k*64 + lane];
    const float bias = prm[OB + lane];
    float* outp = (wvi==0) ? xq : (wvi==1) ? xk : xv;
    const int ptbase = blockIdx.x*32;
    for (int it = 0; it < 32; ++it){
        const int pt = ptbase + it;
        float xl = ldany(x, (long long)pt*64 + lane, f32);
        float acc = bias;
        #pragma unroll
        for (int k = 0; k < 64; ++k) acc += __shfl(xl, k)*Wc[k];
        outp[(size_t)pt*64 + lane] = acc;
        if (wvi){
            unsigned h16, m16; split2(acc, h16, m16);
            unsigned hn = __shfl_down(h16,1), mn = __shfl_down(m16,1);
            if (!(lane & 1)){
                const int u = lane >> 3, pos = u ^ (pt & 7);
                const size_t gi = (size_t)pt*32 + pos*4 + ((lane & 7) >> 1);
                if (wvi == 1){ hkp[gi] = h16 | (hn<<16);  mkp[gi] = m16 | (mn<<16); }
                else         { hvp[gi] = h16 | (hn<<16);  mvp[gi] = m16 | (mn<<16); }
            }
            float s = acc*acc;
            for (int off=32; off; off>>=1) s += __shfl_down(s, off);
            if (lane == 0){ if (wvi == 1) sqk[pt] = s; else sqv[pt] = s; }
        }
    }
}

// ---------------------------------------------------------------- KNN (32x32 MFMA prune + exact re-rank + fused BN1)
// grid 1024 (XCD-swizzled). Block: 64 queries vs ALL 4096 cands (64 chunks).
// Round-9: 32x32x16 MFMA tiling. 4 waves = 2 query-groups (qg) x 2 cand-groups (cg):
// wave (qg,cg) computes queries [qg*32,+32) vs cands [cg*32,+32) of the chunk — each wave
// reads HALF the candidate tile (8KB vs 16KB) => block B-traffic halved (the measured
// LDS-pipe bottleneck). Plane format, staging, swizzle, selection, re-rank: unchanged.
// C/D layout (m74/m101 verified): col=lane&31, row=(reg&3)+8*(reg>>2)+4*(lane>>5).

using bfrag  = __attribute__((ext_vector_type(8))) short;   // 8 x bf16 (4 VGPRs)
using f32x16 = __attribute__((ext_vector_type(16))) float;  // 32x32 MFMA accumulator

// swizzled LDS address (in shorts): row stride 64 shorts (128B), 16B units XOR'd by row&7
__device__ __forceinline__ int lds_sw(int row, int unit){
    return (row<<6) + (((unit ^ row) & 7)<<3);
}

__global__ __launch_bounds__(256, 4) void k_knn_part(
    const float* __restrict__ featk, const float* __restrict__ featv,
    const unsigned* __restrict__ hkp, const unsigned* __restrict__ mkp,
    const unsigned* __restrict__ hvp, const unsigned* __restrict__ mvp,
    const float* __restrict__ sqk, const float* __restrict__ sqv,
    const float* __restrict__ p32, const float* __restrict__ prm,
    int* __restrict__ idx_k, int* __restrict__ idx_v,
    float* __restrict__ part1)
{
    __shared__ __attribute__((aligned(16))) unsigned char smem[34048];
    __shared__ float bn1red[4][6];
    unsigned short* Ch = (unsigned short*)smem;                 // 8KB h-plane tile (swizzled)
    unsigned short* Cm = (unsigned short*)(smem + 8192);        // 8KB m-plane tile
    float* Dt  = (float*)(smem + 16384);                        // 64x68 dist tile (17408B)
    float* sqC = (float*)(smem + 16384 + 17408);                // 256B
    unsigned long long* Lbuf = (unsigned long long*)smem;       // tail overlay (256*6*8=12288B)

    const int tid = threadIdx.x;
    // XCD-aware swizzle: 1024 blocks = 8 XCDs x 128 contiguous logicals
    const int swz = ((int)blockIdx.x & 7) * 128 + ((int)blockIdx.x >> 3);
    const int kid = swz >> 9;
    const int bid = swz & 511;
    const float*    feat = kid ? featv : featk;
    const float*    sq   = kid ? sqv  : sqk;
    const unsigned* hpl  = kid ? hvp : hkp;
    const unsigned* mpl  = kid ? mvp : mkp;
    const int b  = bid >> 6;
    const int qt = bid & 63;
    const int q0 = b*NPB + qt*64;
    const int cb = b*NPB;

    const int lane = tid & 63, wv = tid >> 6;
    const int qg = wv >> 1, cg = wv & 1;             // MFMA role split
    const int l31 = lane & 31, hi = lane >> 5;       // 32x32 fragment lane coords
    const int selq = (wv << 4) + (lane >> 2);        // selection row (0..63)
    const int sub  = lane & 3;
    const int owner = lane & ~3;

    // ---- Q fragments (32x32x16): rows qg*32+l31, k = ks*16 + hi*8 + j  (4 ksteps x 2 planes)
    bfrag qh[4], qm[4];
    {
        const int qr = q0 + (qg<<5) + l31;
        #pragma unroll
        for (int ks = 0; ks < 4; ++ks){
            const int u = ks*2 + hi;                 // 8-dim unit index
            const int pos = u ^ (qr & 7);
            union { uint4 u4; bfrag v; } ch, cm;
            ch.u4 = *(const uint4*)&hpl[(size_t)qr*32 + pos*4];
            cm.u4 = *(const uint4*)&mpl[(size_t)qr*32 + pos*4];
            qh[ks] = ch.v; qm[ks] = cm.v;
        }
    }

    // distributed top-20: 5 sorted entries per sub-lane (ranks sub*5 .. sub*5+4)
    float d5[5]; int i5[5];
    #pragma unroll
    for (int i=0;i<5;++i){ d5[i] = 3.4e38f; i5[i] = 0; }

    // staging base: global offset 16*tid bytes, LDS offset 16*tid bytes (linear copy)
    const unsigned* hrowA = hpl + (size_t)cb*32 + (size_t)tid*4;
    const unsigned* mrowA = mpl + (size_t)cb*32 + (size_t)tid*4;

    #define STAGE(CHN) { \
        const size_t co = (size_t)(CHN)*2048; \
        gll16(hrowA + co,        (void*)&Ch[8*tid]); \
        gll16(hrowA + co + 1024, (void*)&Ch[8*tid + 2048]); \
        gll16(mrowA + co,        (void*)&Cm[8*tid]); \
        gll16(mrowA + co + 1024, (void*)&Cm[8*tid + 2048]); \
        if (tid < 64) gll4(sq + cb + (CHN)*64 + tid, (void*)&sqC[tid]); \
    }

    // 32x32x16 MFMA phase: wave (qg,cg): queries qg*32.. vs cands cg*32.. of the chunk.
    // B frag: cand row cd = cg*32+l31, k = ks*16 + hi*8 + j -> unit u = ks*2+hi, swizzled.
    #define MFMA_PHASE() { \
        const int cd = (cg<<5) + l31; \
        f32x16 acc = {0.f,0.f,0.f,0.f,0.f,0.f,0.f,0.f,0.f,0.f,0.f,0.f,0.f,0.f,0.f,0.f}; \
        _Pragma("unroll") \
        for (int ks = 0; ks < 4; ++ks){ \
            const int u = ks*2 + hi; \
            union { uint4 u4; bfrag v; } bh, bm; \
            bh.u4 = *(const uint4*)&Ch[lds_sw(cd, u)]; \
            bm.u4 = *(const uint4*)&Cm[lds_sw(cd, u)]; \
            acc = __builtin_amdgcn_mfma_f32_32x32x16_bf16(qm[ks], bm.v, acc, 0, 0, 0); \
            acc = __builtin_amdgcn_mfma_f32_32x32x16_bf16(qh[ks], bm.v, acc, 0, 0, 0); \
            acc = __builtin_amdgcn_mfma_f32_32x32x16_bf16(qm[ks], bh.v, acc, 0, 0, 0); \
            acc = __builtin_amdgcn_mfma_f32_32x32x16_bf16(qh[ks], bh.v, acc, 0, 0, 0); \
        } \
        const float sc = sqC[(cg<<5) + l31]; \
        _Pragma("unroll") \
        for (int i = 0; i < 16; ++i){ \
            const int row = (qg<<5) + (i&3) + 8*(i>>2) + 4*hi; \
            Dt[row*68 + (cg<<5) + l31] = sc - 2.f*acc[i]; \
        } }

    // prologue: async-stage chunk 0
    STAGE(0)
    __syncthreads();

    for (int chn = 0; chn < 64; ++chn){
        MFMA_PHASE()                       // planes(chn) -> Dt (cross-wave rows)
        __syncthreads();                   // Dt complete; all waves done reading planes(chn)
        if (chn + 1 < 64) STAGE(chn+1)     // async loads; latency hidden by selection
        // ---- cooperative distributed selection on Dt(chn)
        {
            float worst = __shfl(d5[4], owner+3);     // global rank-19 value
            unsigned m16 = 0;
            const int rowoff = selq*68 + sub*16;
            #pragma unroll
            for (int r = 0; r < 4; ++r){
                float4 v = *(const float4*)&Dt[rowoff + 4*r];
                m16 |= (v.x < worst ? 1u : 0u) << (4*r+0);
                m16 |= (v.y < worst ? 1u : 0u) << (4*r+1);
                m16 |= (v.z < worst ? 1u : 0u) << (4*r+2);
                m16 |= (v.w < worst ? 1u : 0u) << (4*r+3);
            }
            unsigned ma = __shfl(m16, owner+0), mb = __shfl(m16, owner+1);
            unsigned mc = __shfl(m16, owner+2), md = __shfl(m16, owner+3);
            unsigned long long m = (unsigned long long)ma
                                 | ((unsigned long long)mb << 16)
                                 | ((unsigned long long)mc << 32)
                                 | ((unsigned long long)md << 48);
            const int qrow = selq*68;
            const int c0 = cb + chn*64;
            const int prevlane = (lane - 1) & 63;
            while (m){
                int c = (int)__builtin_ctzll(m); m &= m - 1;
                float d = Dt[qrow + c];
                int gi = c0 + c;
                float pl = __shfl(d5[4], prevlane);
                int   pi = __shfl(i5[4], prevlane);
                bool takePrev = (sub != 0) && (pl > d);
                float v  = takePrev ? pl : d;
                int   vi = takePrev ? pi : gi;
                #pragma unroll
                for (int i = 4; i >= 1; --i){
                    bool sh   = d5[i-1] > v;
                    bool here = !sh && (d5[i] > v);
                    d5[i] = sh ? d5[i-1] : (here ? v  : d5[i]);
                    i5[i] = sh ? i5[i-1] : (here ? vi : i5[i]);
                }
                bool h0 = d5[0] > v;
                d5[0] = h0 ? v  : d5[0];
                i5[0] = h0 ? vi : i5[0];
            }
        }
        __syncthreads();                   // sel reads done; vmcnt drained => planes(chn+1) ready
    }
    #undef MFMA_PHASE
    #undef STAGE

    // ---- tail: each lane exact-recomputes its own 5 survivors
    // exact VALU distance — IDENTICAL arithmetic to the proven round-3 code
    unsigned long long k5[5];
    {
        const float* qrow = feat + (size_t)(q0 + selq)*64;
        #pragma unroll
        for (int s = 0; s < 5; ++s){
            const int gi = i5[s];
            const float* crow = feat + (size_t)gi*64;
            float acc = 0.f;
            #pragma unroll
            for (int k4 = 0; k4 < 16; ++k4){
                float4 qv = *(const float4*)&qrow[4*k4];
                float4 cv = *(const float4*)&crow[4*k4];
                acc += qv.x*cv.x; acc += qv.y*cv.y; acc += qv.z*cv.z; acc += qv.w*cv.w;
            }
            float d = sq[gi] - 2.f*acc;
            unsigned ud = __float_as_uint(d);
            ud ^= (ud & 0x80000000u) ? 0xFFFFFFFFu : 0x80000000u;   // order-preserving map
            k5[s] = ((unsigned long long)ud << 32) | (unsigned)gi;  // (d, idx) lexicographic
        }
    }
    // static odd-even sort of 5 keys
    #pragma unroll
    for (int pass = 0; pass < 5; ++pass){
        #pragma unroll
        for (int i = (pass & 1); i + 1 < 5; i += 2){
            unsigned long long a = k5[i], bb = k5[i+1];
            bool sw = a > bb;
            k5[i]   = sw ? bb : a;
            k5[i+1] = sw ? a : bb;
        }
    }
    __syncthreads();   // smem reuse: planes/Dt dead
    #pragma unroll
    for (int j = 0; j < 5; ++j) Lbuf[(size_t)tid*6 + j] = k5[j];
    Lbuf[(size_t)tid*6 + 5] = ~0ull;   // sentinel
    __syncthreads();
    int fi[16];
    #pragma unroll
    for (int i = 0; i < 16; ++i) fi[i] = 0;
    if (sub == 0){
        const unsigned long long* L0 = &Lbuf[(size_t)(tid+0)*6];
        const unsigned long long* L1 = &Lbuf[(size_t)(tid+1)*6];
        const unsigned long long* L2 = &Lbuf[(size_t)(tid+2)*6];
        const unsigned long long* L3 = &Lbuf[(size_t)(tid+3)*6];
        int p0 = 0, p1 = 0, p2 = 0, p3 = 0;
        #pragma unroll
        for (int o = 0; o < 16; ++o){
            unsigned long long b0 = L0[p0], b1v = L1[p1], b2v = L2[p2], b3v = L3[p3];
            unsigned long long m01 = (b0  < b1v) ? b0  : b1v;  int s01 = (b0  < b1v) ? 0 : 1;
            unsigned long long m23 = (b2v < b3v) ? b2v : b3v;  int s23 = (b2v < b3v) ? 2 : 3;
            unsigned long long mm  = (m01 < m23) ? m01 : m23;  int ss  = (m01 < m23) ? s01 : s23;
            fi[o] = (int)(unsigned)(mm & 0xFFFFFFFFull);
            if      (ss == 0) ++p0;
            else if (ss == 1) ++p1;
            else if (ss == 2) ++p2;
            else              ++p3;
        }
        int* idx_out = kid ? idx_v : idx_k;
        #pragma unroll
        for (int i4 = 0; i4 < 4; ++i4)
            *(int4*)&idx_out[(size_t)(q0+selq)*16 + 4*i4] =
                make_int4(fi[4*i4], fi[4*i4+1], fi[4*i4+2], fi[4*i4+3]);
    }

    // ---- fused BN1 partial stats (kid==0 blocks): h = p_rel @ wp1 + bp1 over block's
    // 64 queries x 16 neighbors; 4 neighbors per sub-lane; full-wave butterfly reduce.
    if (kid == 0){
        const float w00=prm[O_WP1+0], w01=prm[O_WP1+1], w02=prm[O_WP1+2];
        const float w10=prm[O_WP1+3], w11=prm[O_WP1+4], w12=prm[O_WP1+5];
        const float w20=prm[O_WP1+6], w21=prm[O_WP1+7], w22=prm[O_WP1+8];
        const float bb0=prm[O_BP1+0], bb1=prm[O_BP1+1], bb2=prm[O_BP1+2];
        const size_t gq = (size_t)(q0 + selq);
        const float px=p32[gq*3+0], py=p32[gq*3+1], pz=p32[gq*3+2];
        float s0=0.f,s1=0.f,s2=0.f,t0=0.f,t1=0.f,t2=0.f;
        #pragma unroll
        for (int o = 0; o < 16; ++o){
            int gi = __shfl(fi[o], owner);
            if ((o & 3) == sub){
                const int j = gi & IMASK;
                float rx = p32[j*3+0]-px, ry = p32[j*3+1]-py, rz = p32[j*3+2]-pz;
                float h0 = bb0 + rx*w00 + ry*w10 + rz*w20;
                float h1 = bb1 + rx*w01 + ry*w11 + rz*w21;
                float h2 = bb2 + rx*w02 + ry*w12 + rz*w22;
                s0+=h0; s1+=h1; s2+=h2; t0+=h0*h0; t1+=h1*h1; t2+=h2*h2;
            }
        }
        #pragma unroll
        for (int off = 1; off < 64; off <<= 1){
            s0+=__shfl_down(s0,off); s1+=__shfl_down(s1,off); s2+=__shfl_down(s2,off);
            t0+=__shfl_down(t0,off); t1+=__shfl_down(t1,off); t2+=__shfl_down(t2,off);
        }
        if (lane == 0){
            bn1red[wv][0]=s0; bn1red[wv][1]=s1; bn1red[wv][2]=s2;
            bn1red[wv][3]=t0; bn1red[wv][4]=t1; bn1red[wv][5]=t2;
        }
        __syncthreads();
        if (tid < 6)
            part1[(size_t)tid*512 + bid] =
                bn1red[0][tid]+bn1red[1][tid]+bn1red[2][tid]+bn1red[3][tid];
    }
}

// ---------------------------------------------------------------- BN reduce (parallel, transposed part[S][G])
// grid = C blocks; block c reduces channels c (sum) and C+c (sumsq), writes aff.
__global__ __launch_bounds__(256) void k_bnred_par(
    const float* __restrict__ part, int G, int C,
    const float* __restrict__ gamma, const float* __restrict__ beta,
    float* __restrict__ aff, float invCount)
{
    __shared__ float rs[4], rq[4];
    const int c = blockIdx.x;
    const int tid = threadIdx.x;
    float s = 0.f, q = 0.f;
    for (int g = tid; g < G; g += 256){
        s += part[(size_t)c*G + g];
        q += part[(size_t)(C+c)*G + g];
    }
    for (int off=32; off; off>>=1){ s += __shfl_down(s,off); q += __shfl_down(q,off); }
    if ((tid & 63) == 0){ rs[tid>>6] = s; rq[tid>>6] = q; }
    __syncthreads();
    if (tid == 0){
        float S = rs[0]+rs[1]+rs[2]+rs[3], Q = rq[0]+rq[1]+rq[2]+rq[3];
        float mean = S*invCount;
        float var  = fmaxf(Q*invCount - mean*mean, 0.f);
        float sc = gamma[c] * rsqrtf(var + EPSB);
        aff[c]   = sc;
        aff[C+c] = beta[c] - mean*sc;
    }
}

// ---------------------------------------------------------------- BN2 stats over r (unrolled x4)
__global__ __launch_bounds__(256) void k_rstats(
    const float* __restrict__ p32,
    const float* __restrict__ xq, const float* __restrict__ xk, const int* __restrict__ idx_k,
    const float* __restrict__ bn1aff, const float* __restrict__ prm,
    float* __restrict__ part2)
{
    const int tid = threadIdx.x, lane = tid & 63, wvi = tid >> 6;
    const float wa = prm[O_WP2+lane], wb = prm[O_WP2+64+lane], wc = prm[O_WP2+128+lane];
    const float bpc = prm[O_BP2+lane];
    const float w00=prm[O_WP1+0], w01=prm[O_WP1+1], w02=prm[O_WP1+2];
    const float w10=prm[O_WP1+3], w11=prm[O_WP1+4], w12=prm[O_WP1+5];
    const float w20=prm[O_WP1+6], w21=prm[O_WP1+7], w22=prm[O_WP1+8];
    const float bb0=prm[O_BP1+0], bb1=prm[O_BP1+1], bb2=prm[O_BP1+2];
    const float sc0=bn1aff[0], sc1=bn1aff[1], sc2=bn1aff[2];
    const float sh0=bn1aff[3], sh1=bn1aff[4], sh2=bn1aff[5];
    const int base = (blockIdx.x*4 + wvi) * 64;
    float asum=0.f, asq=0.f;
    float px=0.f, py=0.f, pz=0.f, xql=0.f;
    for (int e4 = 0; e4 < 16; ++e4){
        const int gb = base + e4*4;
        if ((gb & 15) == 0){
            const int n = gb >> 4;
            px=p32[n*3+0]; py=p32[n*3+1]; pz=p32[n*3+2];
            xql = xq[(size_t)n*64+lane];
        }
        int4 jj = *(const int4*)&idx_k[gb];
        int j[4] = { jj.x & IMASK, jj.y & IMASK, jj.z & IMASK, jj.w & IMASK };
        float kx[4], qx[4][3];
        #pragma unroll
        for (int u=0;u<4;++u){
            qx[u][0]=p32[j[u]*3+0]; qx[u][1]=p32[j[u]*3+1]; qx[u][2]=p32[j[u]*3+2];
            kx[u] = xk[(size_t)j[u]*64+lane];
        }
        #pragma unroll
        for (int u=0;u<4;++u){
            float rx = qx[u][0]-px, ry = qx[u][1]-py, rz = qx[u][2]-pz;
            float h0 = bb0 + rx*w00 + ry*w10 + rz*w20;
            float h1 = bb1 + rx*w01 + ry*w11 + rz*w21;
            float h2 = bb2 + rx*w02 + ry*w12 + rz*w22;
            float r0 = fmaxf(h0*sc0+sh0, 0.f), r1 = fmaxf(h1*sc1+sh1,0.f), r2 = fmaxf(h2*sc2+sh2,0.f);
            float pr = r0*wa + r1*wb + r2*wc + bpc;
            float rv = kx[u] - xql + pr;
            asum += rv; asq += rv*rv;
        }
    }
    __shared__ float red[4][128];
    red[wvi][lane] = asum; red[wvi][64+lane] = asq;
    __syncthreads();
    if (tid < 128)
        part2[(size_t)tid*2048 + blockIdx.x] = red[0][tid]+red[1][tid]+red[2][tid]+red[3][tid];
}

// ---------------------------------------------------------------- BN3 stats over w (+ wbuf store)
__global__ __launch_bounds__(256) void k_wstats(
    const float* __restrict__ p32,
    const float* __restrict__ xq, const float* __restrict__ xk, const int* __restrict__ idx_k,
    const float* __restrict__ bn1aff, const float* __restrict__ prm,
    const float* __restrict__ bn2aff, float* __restrict__ wbuf, float* __restrict__ part3)
{
    __shared__ float4 PRW[64];
    __shared__ float2 SS2[64];
    __shared__ float4 W1A[64], W1B[64];
    const int tid = threadIdx.x;
    if (tid < 64){
        PRW[tid] = make_float4(prm[O_WP2+tid], prm[O_WP2+64+tid], prm[O_WP2+128+tid], prm[O_BP2+tid]);
        SS2[tid] = make_float2(bn2aff[tid], bn2aff[64+tid]);
        W1A[tid] = make_float4(prm[O_WW1+tid*8+0],prm[O_WW1+tid*8+1],prm[O_WW1+tid*8+2],prm[O_WW1+tid*8+3]);
        W1B[tid] = make_float4(prm[O_WW1+tid*8+4],prm[O_WW1+tid*8+5],prm[O_WW1+tid*8+6],prm[O_WW1+tid*8+7]);
    }
    __syncthreads();
    const int g = blockIdx.x*256 + tid;
    const int n = g >> 4;
    const int j = idx_k[g] & IMASK;
    const float w00=prm[O_WP1+0], w01=prm[O_WP1+1], w02=prm[O_WP1+2];
    const float w10=prm[O_WP1+3], w11=prm[O_WP1+4], w12=prm[O_WP1+5];
    const float w20=prm[O_WP1+6], w21=prm[O_WP1+7], w22=prm[O_WP1+8];
    const float bb0=prm[O_BP1+0], bb1=prm[O_BP1+1], bb2=prm[O_BP1+2];
    const float sc0=bn1aff[0], sc1=bn1aff[1], sc2=bn1aff[2];
    const float sh0=bn1aff[3], sh1=bn1aff[4], sh2=bn1aff[5];
    float rx = p32[j*3+0] - p32[n*3+0];
    float ry = p32[j*3+1] - p32[n*3+1];
    float rz = p32[j*3+2] - p32[n*3+2];
    float h0 = bb0 + rx*w00 + ry*w10 + rz*w20;
    float h1 = bb1 + rx*w01 + ry*w11 + rz*w21;
    float h2 = bb2 + rx*w02 + ry*w12 + rz*w22;
    float r0 = fmaxf(h0*sc0+sh0, 0.f), r1 = fmaxf(h1*sc1+sh1,0.f), r2 = fmaxf(h2*sc2+sh2,0.f);
    float wacc[8];
    #pragma unroll
    for (int i=0;i<8;++i) wacc[i] = prm[O_BW1+i];
    const float4* kr = (const float4*)(xk + (size_t)j*64);
    const float4* qr = (const float4*)(xq + (size_t)n*64);
    #pragma unroll
    for (int c4=0;c4<16;++c4){
        float4 kv = kr[c4], qv = qr[c4];
        float kvv[4] = {kv.x,kv.y,kv.z,kv.w};
        float qvv[4] = {qv.x,qv.y,qv.z,qv.w};
        #pragma unroll
        for (int d=0; d<4; ++d){
            int c = 4*c4 + d;
            float4 pw = PRW[c]; float2 ss = SS2[c];
            float pr = r0*pw.x + r1*pw.y + r2*pw.z + pw.w;
            float rr = kvv[d] - qvv[d] + pr;
            float y = fmaxf(rr*ss.x + ss.y, 0.f);
            float4 wA = W1A[c], wB = W1B[c];
            wacc[0]+=y*wA.x; wacc[1]+=y*wA.y; wacc[2]+=y*wA.z; wacc[3]+=y*wA.w;
            wacc[4]+=y*wB.x; wacc[5]+=y*wB.y; wacc[6]+=y*wB.z; wacc[7]+=y*wB.w;
        }
    }
    *(float4*)&wbuf[(size_t)g*8]   = make_float4(wacc[0],wacc[1],wacc[2],wacc[3]);
    *(float4*)&wbuf[(size_t)g*8+4] = make_float4(wacc[4],wacc[5],wacc[6],wacc[7]);
    float st[16];
    #pragma unroll
    for (int i=0;i<8;++i){ st[i]=wacc[i]; st[8+i]=wacc[i]*wacc[i]; }
    for (int off=32; off; off>>=1){
        #pragma unroll
        for (int k=0;k<16;++k) st[k] += __shfl_down(st[k], off);
    }
    __shared__ float red[4][16];
    const int lane = tid&63, wvi = tid>>6;
    if (lane==0){
        #pragma unroll
        for (int k=0;k<16;++k) red[wvi][k]=st[k];
    }
    __syncthreads();
    if (tid < 16)
        part3[(size_t)tid*2048 + blockIdx.x] = red[0][tid]+red[1][tid]+red[2][tid]+red[3][tid];
}

// ---------------------------------------------------------------- final (reads wbuf; no shfl chain)
__global__ __launch_bounds__(256) void k_out(
    const float* __restrict__ p32, const float* __restrict__ xv,
    const int* __restrict__ idx_k, const int* __restrict__ idx_v,
    const float* __restrict__ bn1aff, const float* __restrict__ prm,
    const float* __restrict__ wbuf, const float* __restrict__ bn3aff,
    const int* __restrict__ flags, void* __restrict__ out)
{
    const int tid = threadIdx.x, lane = tid & 63, wvi = tid >> 6;
    const int n = blockIdx.x*4 + wvi;
    const int f32 = flags[0];
    const float w00=prm[O_WP1+0], w01=prm[O_WP1+1], w02=prm[O_WP1+2];
    const float w10=prm[O_WP1+3], w11=prm[O_WP1+4], w12=prm[O_WP1+5];
    const float w20=prm[O_WP1+6], w21=prm[O_WP1+7], w22=prm[O_WP1+8];
    const float bb0=prm[O_BP1+0], bb1=prm[O_BP1+1], bb2=prm[O_BP1+2];
    const float sc0=bn1aff[0], sc1=bn1aff[1], sc2=bn1aff[2];
    const float sh0=bn1aff[3], sh1=bn1aff[4], sh2=bn1aff[5];
    const float wa=prm[O_WP2+lane], wb=prm[O_WP2+64+lane], wc=prm[O_WP2+128+lane];
    const float bpc=prm[O_BP2+lane];
    const int i = lane & 7;
    float s3[8], t3[8], w2col[8];
    #pragma unroll
    for (int m=0;m<8;++m){
        s3[m]=bn3aff[m]; t3[m]=bn3aff[8+m];
        w2col[m]=prm[O_WW2+m*8+i];
    }
    const float bw2i = prm[O_BW2+i];
    const float px=p32[n*3+0], py=p32[n*3+1], pz=p32[n*3+2];
    float comb[16], wf[16];
    #pragma unroll
    for (int t=0;t<16;++t){
        const int g = n*16 + t;
        const int jk = idx_k[g] & IMASK;
        const int jv = idx_v[g] & IMASK;
        float rx=p32[jk*3+0]-px, ry=p32[jk*3+1]-py, rz=p32[jk*3+2]-pz;
        float h0=bb0+rx*w00+ry*w10+rz*w20;
        float h1=bb1+rx*w01+ry*w11+rz*w21;
        float h2=bb2+rx*w02+ry*w12+rz*w22;
        float r0=fmaxf(h0*sc0+sh0,0.f), r1=fmaxf(h1*sc1+sh1,0.f), r2=fmaxf(h2*sc2+sh2,0.f);
        float pr=r0*wa+r1*wb+r2*wc+bpc;
        float4 wA = *(const float4*)&wbuf[(size_t)g*8];
        float4 wB = *(const float4*)&wbuf[(size_t)g*8+4];
        float wm[8] = {wA.x,wA.y,wA.z,wA.w,wB.x,wB.y,wB.z,wB.w};
        float acc = bw2i;
        #pragma unroll
        for (int m=0;m<8;++m){
            float y3 = fmaxf(wm[m]*s3[m]+t3[m],0.f);
            acc += y3*w2col[m];
        }
        wf[t]=acc;
        comb[t]=xv[(size_t)jv*64+lane]+pr;
    }
    float mx = wf[0];
    #pragma unroll
    for (int t=1;t<16;++t) mx = fmaxf(mx, wf[t]);
    float ssum=0.f, osum=0.f;
    #pragma unroll
    for (int t=0;t<16;++t){ float e = __expf(wf[t]-mx); ssum += e; osum += e*comb[t]; }
    const float v = osum / ssum;
    if (f32) ((float*)out)[(size_t)n*64+lane] = v;
    else     ((bf16*)out)[(size_t)n*64+lane] = __float2bfloat16(v);
}

// ---------------------------------------------------------------- launcher
extern "C" void kernel_launch(void* const* d_in, const int* in_sizes, int n_in,
                              void* d_out, int out_size, void* d_ws, size_t ws_size,
                              hipStream_t stream)
{
    const void* p  = d_in[0];
    const void* x  = d_in[1];
    P20 prms;
    for (int i = 0; i < 20; ++i) prms.p[i] = d_in[3+i];

    // workspace layout (floats) — within the 48.08 MB proven footprint
    float* W = (float*)d_ws;
    float* xqf    = W + 0;
    float* xkf    = W + 2097152;
    float* xvf    = W + 4194304;
    float* sqk    = W + 6291456;
    float* sqv    = W + 6324224;
    int*   idx_k  = (int*)(W + 6356992);
    int*   idx_v  = (int*)(W + 6881280);
    float* p32    = W + 7405568;   // 98304
    float* prm    = W + 7503872;   // 13490 (+pad)
    float* part1  = W + 7517376;   // transposed [6][512] = 3072 (slot 12288)
    float* part2  = W + 7529664;   // transposed [128][2048] = 262144
    float* part3  = W + 7791808;   // transposed [16][2048] = 32768
    float* bn1aff = W + 7824576;   // 16
    float* bn2aff = W + 7824592;   // 128
    float* bn3aff = W + 7824720;   // 16
    int*   flags  = (int*)(W + 7824736); // 2 (+pad to 16)
    // overlay region (4,194,304 floats): bf16 h/m planes (live: k_proj -> k_knn_part),
    // then wbuf (written k_wstats, read k_out) — disjoint lifetimes.
    unsigned* hkp = (unsigned*)(W + 7824752);             // 1,048,576 u32
    unsigned* mkp = (unsigned*)(W + 7824752 + 1048576);
    unsigned* hvp = (unsigned*)(W + 7824752 + 2097152);
    unsigned* mvp = (unsigned*)(W + 7824752 + 3145728);
    float* wbuf   = W + 7824752;   // 4,194,304

    const float invP = 1.f / (float)NPAIR;

    k_conv<<<(NPRM + NPTS*3 + 255)/256,256,0,stream>>>(prms, p, x, d_in[3], prm, p32, flags);
    k_proj<<<1024,192,0,stream>>>(x, flags, prm, xqf,xkf,xvf, sqk,sqv, hkp,mkp,hvp,mvp);
    k_knn_part<<<1024,256,0,stream>>>(xkf, xvf, hkp,mkp,hvp,mvp, sqk, sqv,
                                      p32, prm, idx_k, idx_v, part1);
    k_bnred_par<<<3,256,0,stream>>>(part1, 512, 3, prm+O_GP, prm+O_BTP, bn1aff, invP);
    k_rstats<<<2048,256,0,stream>>>(p32, xqf, xkf, idx_k, bn1aff, prm, part2);
    k_bnred_par<<<64,256,0,stream>>>(part2, 2048, 64, prm+O_G1, prm+O_BT1, bn2aff, invP);
    k_wstats<<<2048,256,0,stream>>>(p32, xqf, xkf, idx_k, bn1aff, prm, bn2aff, wbuf, part3);
    k_bnred_par<<<8,256,0,stream>>>(part3, 2048, 8, prm+O_G2, prm+O_BT2, bn3aff, invP);
    k_out<<<8192,256,0,stream>>>(p32, xvf, idx_k, idx_v, bn1aff, prm,
                                 wbuf, bn3aff, flags, d_out);
}